// Round 14
// baseline (66.295 us; speedup 1.0000x reference)
//
#include <hip/hip_runtime.h>
#include <hip/hip_bf16.h>
#include <math.h>

#define N_NODES 2048
#define FIN 128
#define FOUT 64
#define BS 8
#define ALPHA 0.2f
#define LOG2E 1.4426950408889634f

typedef __attribute__((ext_vector_type(8))) short short8v;
typedef __attribute__((ext_vector_type(4))) float f32x4;

__device__ __forceinline__ unsigned int pack2bf(float a, float b) {
  __hip_bfloat162 t = __float22bfloat162_rn(make_float2(a, b));
  unsigned int r;
  __builtin_memcpy(&r, &t, 4);
  return r;
}
// hi/lo bf16 split of a float pair via packed cvt (RNE)
__device__ __forceinline__ void split2(float f0, float f1, unsigned &hi, unsigned &lo) {
  hi = pack2bf(f0, f1);
  const float h0 = __uint_as_float(hi << 16);
  const float h1 = __uint_as_float(hi & 0xFFFF0000u);
  lo = pack2bf(f0 - h0, f1 - h1);
}
__device__ __forceinline__ float exp2_raw(float x) {
  float r;
  asm volatile("v_exp_f32 %0, %1\n\ts_nop 1" : "=v"(r) : "v"(x));
  return r;
}
__device__ __forceinline__ float elu_f(float v) {
  return v > 0.f ? v : expm1f(v);
}

// ---------------- gat_prep: identical to R11 (best) ---------------------------
__global__ __launch_bounds__(256, 4) void gat_prep(const float* __restrict__ x,
                                                   const int* __restrict__ adj,
                                                   const float* __restrict__ W,
                                                   const float* __restrict__ a,
                                                   short* __restrict__ hp,
                                                   float* __restrict__ s1,
                                                   float* __restrict__ s2,
                                                   unsigned int* __restrict__ mask32) {
  const int bx = blockIdx.x;            // 0..1023
  const int b = bx >> 7;
  const int t16 = bx & 127;
  const int i0 = t16 * 16;
  const int w = threadIdx.x >> 6, lane = threadIdx.x & 63;
  const int kg = lane >> 4, rl = lane & 15;

  __shared__ float h_lds[16][68];

  const int mrow_id = 2 * bx + (w >> 1);
  const int* ar = adj + (long long)mrow_id * N_NODES + (w & 1) * 1024;
  int mreg[16];
  #pragma unroll
  for (int c = 0; c < 16; ++c) mreg[c] = ar[c * 64 + lane];

  const float* xB = x + ((long long)b * N_NODES + i0 + rl) * FIN + kg * 8;
  float4 xv[8];
  #pragma unroll
  for (int i = 0; i < 8; ++i)
    xv[i] = *reinterpret_cast<const float4*>(xB + (i >> 1) * 32 + (i & 1) * 4);

  union u8s { short8v v; unsigned u[4]; };
  u8s bh[4], bl[4];
  #pragma unroll
  for (int ks = 0; ks < 4; ++ks) {
    #pragma unroll
    for (int pe = 0; pe < 4; ++pe) {
      const float w0 = W[(ks * 32 + kg * 8 + 2 * pe) * FOUT + w * 16 + rl];
      const float w1 = W[(ks * 32 + kg * 8 + 2 * pe + 1) * FOUT + w * 16 + rl];
      split2(w0, w1, bh[ks].u[pe], bl[ks].u[pe]);
    }
  }

  f32x4 ahh = {0.f, 0.f, 0.f, 0.f};
  f32x4 ahl = {0.f, 0.f, 0.f, 0.f};
  f32x4 alh = {0.f, 0.f, 0.f, 0.f};
  #pragma unroll
  for (int ks = 0; ks < 4; ++ks) {
    const float4 xa = xv[2 * ks], xb = xv[2 * ks + 1];
    const float xf[8] = {xa.x, xa.y, xa.z, xa.w, xb.x, xb.y, xb.z, xb.w};
    u8s xh, xl;
    #pragma unroll
    for (int pe = 0; pe < 4; ++pe)
      split2(xf[2 * pe], xf[2 * pe + 1], xh.u[pe], xl.u[pe]);
    ahh = __builtin_amdgcn_mfma_f32_16x16x32_bf16(xh.v, bh[ks].v, ahh, 0, 0, 0);
    ahl = __builtin_amdgcn_mfma_f32_16x16x32_bf16(xh.v, bl[ks].v, ahl, 0, 0, 0);
    alh = __builtin_amdgcn_mfma_f32_16x16x32_bf16(xl.v, bh[ks].v, alh, 0, 0, 0);
  }
  const f32x4 acc = (ahh + ahl) + alh;
  #pragma unroll
  for (int r = 0; r < 4; ++r)
    h_lds[kg * 4 + r][w * 16 + rl] = acc[r];

  {
    unsigned int* mw = mask32 + mrow_id * 64 + (w & 1) * 32;
    #pragma unroll
    for (int c = 0; c < 16; ++c) {
      const unsigned long long bal = __ballot(mreg[c] > 0);
      if (lane == 0) mw[2 * c] = (unsigned int)bal;
      if (lane == 1) mw[2 * c + 1] = (unsigned int)(bal >> 32);
    }
  }

  __syncthreads();

  {
    const float a1v = a[lane], a2v = a[FOUT + lane];
    #pragma unroll
    for (int rr = 0; rr < 4; ++rr) {
      const float hv = h_lds[4 * w + rr][lane];
      float p = hv * a1v, q = hv * a2v;
      #pragma unroll
      for (int off = 32; off > 0; off >>= 1) {
        p += __shfl_xor(p, off);
        q += __shfl_xor(q, off);
      }
      if (lane == 0) {
        s1[(long long)b * N_NODES + i0 + 4 * w + rr] = p * LOG2E;
        s2[(long long)b * N_NODES + i0 + 4 * w + rr] = q * LOG2E;
      }
    }
  }

  if (lane < 32) {
    const int jt = t16 >> 1, kh = t16 & 1;
    const int kgl = lane >> 4, col = lane & 15;
    u8s o;
    #pragma unroll
    for (int i = 0; i < 4; ++i)
      o.u[i] = pack2bf(h_lds[kgl * 8 + 2 * i][w * 16 + col],
                       h_lds[kgl * 8 + 2 * i + 1][w * 16 + col]);
    *reinterpret_cast<short8v*>(
        hp + (((long long)(b * 256 + jt * 4 + w)) * 64 + (kh * 2 + kgl) * 16 + col) * 8) = o.v;
  }
}

// ---------------- gat_attn: identical to R11 (best) ---------------------------
__global__ __launch_bounds__(512, 4) void gat_attn(const unsigned int* __restrict__ mask32,
                                                   const short* __restrict__ hp,
                                                   const float* __restrict__ s1g,
                                                   const float* __restrict__ s2g,
                                                   float* __restrict__ out) {
  const int b = blockIdx.y;
  const int i0 = blockIdx.x * 32;
  const int t = threadIdx.x;
  const int w = t >> 6, lane = t & 63;
  const int kg = lane >> 4, rl = lane & 15;

  __shared__ float red[8][16 * 64];   // 32 KB
  __shared__ float ps[8][16];
  __shared__ uint2 lut[16];           // nibble -> 2 packed-bf16 AND-masks

  if (t < 16) {
    const unsigned v = t;
    lut[t].x = ((v & 1u) ? 0xFFFFu : 0u) | ((v & 2u) ? 0xFFFF0000u : 0u);
    lut[t].y = ((v & 4u) ? 0xFFFFu : 0u) | ((v & 8u) ? 0xFFFF0000u : 0u);
  }
  __syncthreads();

  const float s1v1 = s1g[b * N_NODES + i0 + rl];
  const float s1v2 = s1g[b * N_NODES + i0 + 16 + rl];
  const float* s2B = s2g + b * N_NODES;
  const unsigned int* mrow1 = mask32 + (i0 + rl) * 64;
  const unsigned int* mrow2 = mask32 + (i0 + 16 + rl) * 64;
  const short8v* hpB = reinterpret_cast<const short8v*>(hp) + (long long)b * 16384;

  f32x4 a10 = {0.f, 0.f, 0.f, 0.f}, a11 = {0.f, 0.f, 0.f, 0.f};
  f32x4 a12 = {0.f, 0.f, 0.f, 0.f}, a13 = {0.f, 0.f, 0.f, 0.f};
  f32x4 a20 = {0.f, 0.f, 0.f, 0.f}, a21 = {0.f, 0.f, 0.f, 0.f};
  f32x4 a22 = {0.f, 0.f, 0.f, 0.f}, a23 = {0.f, 0.f, 0.f, 0.f};
  f32x4 aS1 = {0.f, 0.f, 0.f, 0.f}, aS2 = {0.f, 0.f, 0.f, 0.f};
  union u8s { short8v v; unsigned u[4]; };
  u8s ones;
  #pragma unroll
  for (int i = 0; i < 4; ++i) ones.u[i] = 0x3F803F80u;

  #pragma unroll
  for (int k = 0; k < 8; ++k) {
    const int jt = w + 8 * k;
    const short8v* hpt = hpB + jt * 256;
    const short8v b0 = hpt[0 * 64 + lane];
    const short8v b1 = hpt[1 * 64 + lane];
    const short8v b2 = hpt[2 * 64 + lane];
    const short8v b3 = hpt[3 * 64 + lane];
    const float4 sa = *reinterpret_cast<const float4*>(s2B + jt * 32 + kg * 8);
    const float4 sb = *reinterpret_cast<const float4*>(s2B + jt * 32 + kg * 8 + 4);
    const unsigned int m1 = (mrow1[jt] >> (kg * 8)) & 0xFFu;
    const unsigned int m2 = (mrow2[jt] >> (kg * 8)) & 0xFFu;
    const uint2 k10 = lut[m1 & 15u], k11 = lut[m1 >> 4];
    const uint2 k20 = lut[m2 & 15u], k21 = lut[m2 >> 4];
    const float s2e[8] = {sa.x, sa.y, sa.z, sa.w, sb.x, sb.y, sb.z, sb.w};
    float p1[8], p2[8];
    #pragma unroll
    for (int e = 0; e < 8; e++) {
      float sc1 = s1v1 + s2e[e];
      float sc2 = s2e[e] + s1v2;
      sc1 = fmaxf(sc1, ALPHA * sc1);          // leaky-relu (exp2 domain)
      sc2 = fmaxf(sc2, ALPHA * sc2);
      p1[e] = exp2_raw(sc1);
      p2[e] = exp2_raw(sc2);
    }
    u8s af1, af2;
    af1.u[0] = pack2bf(p1[0], p1[1]) & k10.x;
    af1.u[1] = pack2bf(p1[2], p1[3]) & k10.y;
    af1.u[2] = pack2bf(p1[4], p1[5]) & k11.x;
    af1.u[3] = pack2bf(p1[6], p1[7]) & k11.y;
    af2.u[0] = pack2bf(p2[0], p2[1]) & k20.x;
    af2.u[1] = pack2bf(p2[2], p2[3]) & k20.y;
    af2.u[2] = pack2bf(p2[4], p2[5]) & k21.x;
    af2.u[3] = pack2bf(p2[6], p2[7]) & k21.y;
    a10 = __builtin_amdgcn_mfma_f32_16x16x32_bf16(af1.v, b0, a10, 0, 0, 0);
    a20 = __builtin_amdgcn_mfma_f32_16x16x32_bf16(af2.v, b0, a20, 0, 0, 0);
    a11 = __builtin_amdgcn_mfma_f32_16x16x32_bf16(af1.v, b1, a11, 0, 0, 0);
    a21 = __builtin_amdgcn_mfma_f32_16x16x32_bf16(af2.v, b1, a21, 0, 0, 0);
    a12 = __builtin_amdgcn_mfma_f32_16x16x32_bf16(af1.v, b2, a12, 0, 0, 0);
    a22 = __builtin_amdgcn_mfma_f32_16x16x32_bf16(af2.v, b2, a22, 0, 0, 0);
    a13 = __builtin_amdgcn_mfma_f32_16x16x32_bf16(af1.v, b3, a13, 0, 0, 0);
    a23 = __builtin_amdgcn_mfma_f32_16x16x32_bf16(af2.v, b3, a23, 0, 0, 0);
    aS1 = __builtin_amdgcn_mfma_f32_16x16x32_bf16(af1.v, ones.v, aS1, 0, 0, 0);
    aS2 = __builtin_amdgcn_mfma_f32_16x16x32_bf16(af2.v, ones.v, aS2, 0, 0, 0);
  }

  // ---- phase 1: rows i0..i0+15 ----
  #pragma unroll
  for (int r = 0; r < 4; r++) {
    red[w][(kg * 4 + r) * 64 + 0 * 16 + rl] = a10[r];
    red[w][(kg * 4 + r) * 64 + 1 * 16 + rl] = a11[r];
    red[w][(kg * 4 + r) * 64 + 2 * 16 + rl] = a12[r];
    red[w][(kg * 4 + r) * 64 + 3 * 16 + rl] = a13[r];
  }
  if (rl == 0) {
    #pragma unroll
    for (int r = 0; r < 4; r++) ps[w][kg * 4 + r] = aS1[r];
  }
  __syncthreads();
  {
    const int row = t >> 5;
    const int c2 = (t & 31) * 2;
    float den = 0.f, v0 = 0.f, v1 = 0.f;
    #pragma unroll
    for (int s = 0; s < 8; ++s) {
      den += ps[s][row];
      const float* rp = &red[s][row * 64 + c2];
      v0 += rp[0]; v1 += rp[1];
    }
    const float inv = 1.0f / den;
    float2 ov;
    ov.x = elu_f(v0 * inv);
    ov.y = elu_f(v1 * inv);
    *reinterpret_cast<float2*>(
        out + ((long long)b * N_NODES + i0 + row) * FOUT + c2) = ov;
  }
  __syncthreads();

  // ---- phase 2: rows i0+16..i0+31 ----
  #pragma unroll
  for (int r = 0; r < 4; r++) {
    red[w][(kg * 4 + r) * 64 + 0 * 16 + rl] = a20[r];
    red[w][(kg * 4 + r) * 64 + 1 * 16 + rl] = a21[r];
    red[w][(kg * 4 + r) * 64 + 2 * 16 + rl] = a22[r];
    red[w][(kg * 4 + r) * 64 + 3 * 16 + rl] = a23[r];
  }
  if (rl == 0) {
    #pragma unroll
    for (int r = 0; r < 4; r++) ps[w][kg * 4 + r] = aS2[r];
  }
  __syncthreads();
  {
    const int row = t >> 5;
    const int c2 = (t & 31) * 2;
    float den = 0.f, v0 = 0.f, v1 = 0.f;
    #pragma unroll
    for (int s = 0; s < 8; ++s) {
      den += ps[s][row];
      const float* rp = &red[s][row * 64 + c2];
      v0 += rp[0]; v1 += rp[1];
    }
    const float inv = 1.0f / den;
    float2 ov;
    ov.x = elu_f(v0 * inv);
    ov.y = elu_f(v1 * inv);
    *reinterpret_cast<float2*>(
        out + ((long long)b * N_NODES + i0 + 16 + row) * FOUT + c2) = ov;
  }
}

extern "C" void kernel_launch(void* const* d_in, const int* in_sizes, int n_in,
                              void* d_out, int out_size, void* d_ws, size_t ws_size,
                              hipStream_t stream) {
  const float* x   = (const float*)d_in[0];
  const int*   adj = (const int*)d_in[1];
  const float* W   = (const float*)d_in[2];
  const float* a   = (const float*)d_in[3];
  float* out = (float*)d_out;

  short* hp = (short*)d_ws;                                        // 2 MB
  float* s1 = (float*)(hp + (long long)BS * N_NODES * FOUT);       // 64 KB
  float* s2 = s1 + BS * N_NODES;                                   // 64 KB
  unsigned int* mask32 = (unsigned int*)(s2 + BS * N_NODES);       // 512 KB

  gat_prep<<<1024, 256, 0, stream>>>(x, adj, W, a, hp, s1, s2, mask32);
  // MEASUREMENT ROUND: attn launched 3x (idempotent -- same inputs, same out).
  // attn_standalone = (dur_R14 - dur_R11) / 2.
  gat_attn<<<dim3(N_NODES / 32, BS), 512, 0, stream>>>(mask32, hp, s1, s2, out);
  gat_attn<<<dim3(N_NODES / 32, BS), 512, 0, stream>>>(mask32, hp, s1, s2, out);
  gat_attn<<<dim3(N_NODES / 32, BS), 512, 0, stream>>>(mask32, hp, s1, s2, out);
}

// Round 15
// 32.561 us; speedup vs baseline: 2.0360x; 2.0360x over previous
//
#include <hip/hip_runtime.h>
#include <hip/hip_bf16.h>
#include <math.h>

#define N_NODES 2048
#define FIN 128
#define FOUT 64
#define BS 8
#define ALPHA 0.2f
#define LOG2E 1.4426950408889634f

typedef __attribute__((ext_vector_type(8))) short short8v;
typedef __attribute__((ext_vector_type(4))) float f32x4;

__device__ __forceinline__ unsigned int pack2bf(float a, float b) {
  __hip_bfloat162 t = __float22bfloat162_rn(make_float2(a, b));
  unsigned int r;
  __builtin_memcpy(&r, &t, 4);
  return r;
}
// hi/lo bf16 split of a float pair via packed cvt (RNE)
__device__ __forceinline__ void split2(float f0, float f1, unsigned &hi, unsigned &lo) {
  hi = pack2bf(f0, f1);
  const float h0 = __uint_as_float(hi << 16);
  const float h1 = __uint_as_float(hi & 0xFFFF0000u);
  lo = pack2bf(f0 - h0, f1 - h1);
}
__device__ __forceinline__ float exp2_raw(float x) {
  float r;
  asm volatile("v_exp_f32 %0, %1\n\ts_nop 1" : "=v"(r) : "v"(x));
  return r;
}
__device__ __forceinline__ float elu_f(float v) {
  return v > 0.f ? v : expm1f(v);
}

// ---------------- w_pack: W -> bf16 hi/lo B-fragments (16 frags, 1 wave each) -
// frag f = ks*4+ct; element (lane=(kg,rl), e) = W[ks*32+kg*8+e][ct*16+rl].
__global__ __launch_bounds__(64) void w_pack(const float* __restrict__ W,
                                             short* __restrict__ whi,
                                             short* __restrict__ wlo) {
  const int f = blockIdx.x;            // 0..15
  const int lane = threadIdx.x;
  const int kg = lane >> 4, rl = lane & 15;
  const int ks = f >> 2, ct = f & 3;
  float wv[8];
  #pragma unroll
  for (int e = 0; e < 8; ++e)
    wv[e] = W[(ks * 32 + kg * 8 + e) * FOUT + ct * 16 + rl];
  union u8s { short8v v; unsigned u[4]; };
  u8s hi, lo;
  #pragma unroll
  for (int pe = 0; pe < 4; ++pe)
    split2(wv[2 * pe], wv[2 * pe + 1], hi.u[pe], lo.u[pe]);
  *reinterpret_cast<short8v*>(whi + ((long long)f * 64 + lane) * 8) = hi.v;
  *reinterpret_cast<short8v*>(wlo + ((long long)f * 64 + lane) * 8) = lo.v;
}

// ---------------- gat_prep: MFMA h + s1/s2 + hp/mask pack ---------------------
// 1024 blocks x 256 threads (4 waves). W frags: coalesced pre-packed loads.
// x staged via LDS (coalesced global -> b128 LDS reads).
__global__ __launch_bounds__(256, 4) void gat_prep(const float* __restrict__ x,
                                                   const int* __restrict__ adj,
                                                   const short* __restrict__ whi,
                                                   const short* __restrict__ wlo,
                                                   const float* __restrict__ a,
                                                   short* __restrict__ hp,
                                                   float* __restrict__ s1,
                                                   float* __restrict__ s2,
                                                   unsigned int* __restrict__ mask32) {
  const int bx = blockIdx.x;            // 0..1023
  const int b = bx >> 7;
  const int t16 = bx & 127;
  const int i0 = t16 * 16;
  const int t = threadIdx.x;
  const int w = t >> 6, lane = t & 63;
  const int kg = lane >> 4, rl = lane & 15;

  __shared__ float x_lds[16][132];      // 8.4 KB
  __shared__ float h_lds[16][68];       // 4.4 KB

  // ---- issue adj loads first (16 outstanding) ----
  const int mrow_id = 2 * bx + (w >> 1);
  const int* ar = adj + (long long)mrow_id * N_NODES + (w & 1) * 1024;
  int mreg[16];
  #pragma unroll
  for (int c = 0; c < 16; ++c) mreg[c] = ar[c * 64 + lane];

  // ---- coop x stage: thread t -> row t>>4, cols (t&15)*8 .. +7 (coalesced) ----
  {
    const float* xrow = x + ((long long)b * N_NODES + i0 + (t >> 4)) * FIN + (t & 15) * 8;
    const float4 xa = *reinterpret_cast<const float4*>(xrow);
    const float4 xb = *reinterpret_cast<const float4*>(xrow + 4);
    *reinterpret_cast<float4*>(&x_lds[t >> 4][(t & 15) * 8]) = xa;
    *reinterpret_cast<float4*>(&x_lds[t >> 4][(t & 15) * 8 + 4]) = xb;
  }

  // ---- W fragments: coalesced 16B loads of pre-packed hi/lo ----
  union u8s { short8v v; unsigned u[4]; };
  short8v bh[4], bl[4];
  #pragma unroll
  for (int ks = 0; ks < 4; ++ks) {
    bh[ks] = *reinterpret_cast<const short8v*>(whi + ((long long)((ks * 4 + w) * 64 + lane)) * 8);
    bl[ks] = *reinterpret_cast<const short8v*>(wlo + ((long long)((ks * 4 + w) * 64 + lane)) * 8);
  }

  __syncthreads();   // x_lds ready

  // ---- h tile via 3-term MFMA; x from LDS ----
  f32x4 ahh = {0.f, 0.f, 0.f, 0.f};
  f32x4 ahl = {0.f, 0.f, 0.f, 0.f};
  f32x4 alh = {0.f, 0.f, 0.f, 0.f};
  #pragma unroll
  for (int ks = 0; ks < 4; ++ks) {
    const float4 xa = *reinterpret_cast<const float4*>(&x_lds[rl][ks * 32 + kg * 8]);
    const float4 xb = *reinterpret_cast<const float4*>(&x_lds[rl][ks * 32 + kg * 8 + 4]);
    const float xf[8] = {xa.x, xa.y, xa.z, xa.w, xb.x, xb.y, xb.z, xb.w};
    u8s xh, xl;
    #pragma unroll
    for (int pe = 0; pe < 4; ++pe)
      split2(xf[2 * pe], xf[2 * pe + 1], xh.u[pe], xl.u[pe]);
    ahh = __builtin_amdgcn_mfma_f32_16x16x32_bf16(xh.v, bh[ks], ahh, 0, 0, 0);
    ahl = __builtin_amdgcn_mfma_f32_16x16x32_bf16(xh.v, bl[ks], ahl, 0, 0, 0);
    alh = __builtin_amdgcn_mfma_f32_16x16x32_bf16(xl.v, bh[ks], alh, 0, 0, 0);
  }
  const f32x4 acc = (ahh + ahl) + alh;
  #pragma unroll
  for (int r = 0; r < 4; ++r)
    h_lds[kg * 4 + r][w * 16 + rl] = acc[r];

  // ---- mask ballots on the prefetched regs ----
  {
    unsigned int* mw = mask32 + mrow_id * 64 + (w & 1) * 32;
    #pragma unroll
    for (int c = 0; c < 16; ++c) {
      const unsigned long long bal = __ballot(mreg[c] > 0);
      if (lane == 0) mw[2 * c] = (unsigned int)bal;
      if (lane == 1) mw[2 * c + 1] = (unsigned int)(bal >> 32);
    }
  }

  __syncthreads();   // h_lds ready

  // ---- s1/s2 (scaled by log2e for exp2-domain attn) ----
  {
    const float a1v = a[lane], a2v = a[FOUT + lane];
    #pragma unroll
    for (int rr = 0; rr < 4; ++rr) {
      const float hv = h_lds[4 * w + rr][lane];
      float p = hv * a1v, q = hv * a2v;
      #pragma unroll
      for (int off = 32; off > 0; off >>= 1) {
        p += __shfl_xor(p, off);
        q += __shfl_xor(q, off);
      }
      if (lane == 0) {
        s1[(long long)b * N_NODES + i0 + 4 * w + rr] = p * LOG2E;
        s2[(long long)b * N_NODES + i0 + 4 * w + rr] = q * LOG2E;
      }
    }
  }

  // ---- hp pack: wave w = ct; this 16-row tile is k-half kh of hp tile jt ----
  if (lane < 32) {
    const int jt = t16 >> 1, kh = t16 & 1;
    const int kgl = lane >> 4, col = lane & 15;
    u8s o;
    #pragma unroll
    for (int i = 0; i < 4; ++i)
      o.u[i] = pack2bf(h_lds[kgl * 8 + 2 * i][w * 16 + col],
                       h_lds[kgl * 8 + 2 * i + 1][w * 16 + col]);
    *reinterpret_cast<short8v*>(
        hp + (((long long)(b * 256 + jt * 4 + w)) * 64 + (kh * 2 + kgl) * 16 + col) * 8) = o.v;
  }
}

// ---------------- gat_attn: LDS-staged masks + s2; exp2 + LUT masking --------
// Grid (64 i-tiles, 8 b), 512 threads = 8 waves, wave w = j-stripe w.
// mask rows + s2 row staged into the epilogue's red buffer (overlaid).
__global__ __launch_bounds__(512, 4) void gat_attn(const unsigned int* __restrict__ mask32,
                                                   const short* __restrict__ hp,
                                                   const float* __restrict__ s1g,
                                                   const float* __restrict__ s2g,
                                                   float* __restrict__ out) {
  const int b = blockIdx.y;
  const int i0 = blockIdx.x * 32;
  const int t = threadIdx.x;
  const int w = t >> 6, lane = t & 63;
  const int kg = lane >> 4, rl = lane & 15;

  __shared__ float red[8][1024];      // 32 KB; first 16.3 KB overlaid in main loop
  __shared__ float ps[8][16];
  __shared__ uint2 lut[16];

  unsigned int* mask_lds = reinterpret_cast<unsigned int*>(&red[0][0]);  // [32][65]
  float* s2_lds = &red[0][0] + 2080;                                     // 2048 floats

  if (t < 16) {
    const unsigned v = t;
    lut[t].x = ((v & 1u) ? 0xFFFFu : 0u) | ((v & 2u) ? 0xFFFF0000u : 0u);
    lut[t].y = ((v & 4u) ? 0xFFFFu : 0u) | ((v & 8u) ? 0xFFFF0000u : 0u);
  }
  // ---- stage 32 mask rows (coalesced uint4, scatter to [row][65]) ----
  {
    const uint4 mv = reinterpret_cast<const uint4*>(mask32 + i0 * 64)[t];
    const int row = t >> 4, col = (t & 15) * 4;
    mask_lds[row * 65 + col + 0] = mv.x;
    mask_lds[row * 65 + col + 1] = mv.y;
    mask_lds[row * 65 + col + 2] = mv.z;
    mask_lds[row * 65 + col + 3] = mv.w;
  }
  // ---- stage s2 row (2048 floats, coalesced) ----
  {
    const float4 sv = reinterpret_cast<const float4*>(s2g + b * N_NODES)[t];
    *reinterpret_cast<float4*>(&s2_lds[t * 4]) = sv;
  }
  __syncthreads();

  const float s1v1 = s1g[b * N_NODES + i0 + rl];
  const float s1v2 = s1g[b * N_NODES + i0 + 16 + rl];
  const short8v* hpB = reinterpret_cast<const short8v*>(hp) + (long long)b * 16384;

  f32x4 a10 = {0.f, 0.f, 0.f, 0.f}, a11 = {0.f, 0.f, 0.f, 0.f};
  f32x4 a12 = {0.f, 0.f, 0.f, 0.f}, a13 = {0.f, 0.f, 0.f, 0.f};
  f32x4 a20 = {0.f, 0.f, 0.f, 0.f}, a21 = {0.f, 0.f, 0.f, 0.f};
  f32x4 a22 = {0.f, 0.f, 0.f, 0.f}, a23 = {0.f, 0.f, 0.f, 0.f};
  f32x4 aS1 = {0.f, 0.f, 0.f, 0.f}, aS2 = {0.f, 0.f, 0.f, 0.f};
  union u8s { short8v v; unsigned u[4]; };
  u8s ones;
  #pragma unroll
  for (int i = 0; i < 4; ++i) ones.u[i] = 0x3F803F80u;

  #pragma unroll
  for (int k = 0; k < 8; ++k) {
    const int jt = w + 8 * k;
    const short8v* hpt = hpB + jt * 256;
    const short8v b0 = hpt[0 * 64 + lane];
    const short8v b1 = hpt[1 * 64 + lane];
    const short8v b2 = hpt[2 * 64 + lane];
    const short8v b3 = hpt[3 * 64 + lane];
    const float4 sa = *reinterpret_cast<const float4*>(&s2_lds[jt * 32 + kg * 8]);
    const float4 sb = *reinterpret_cast<const float4*>(&s2_lds[jt * 32 + kg * 8 + 4]);
    const unsigned int m1 = (mask_lds[rl * 65 + jt] >> (kg * 8)) & 0xFFu;
    const unsigned int m2 = (mask_lds[(16 + rl) * 65 + jt] >> (kg * 8)) & 0xFFu;
    const uint2 k10 = lut[m1 & 15u], k11 = lut[m1 >> 4];
    const uint2 k20 = lut[m2 & 15u], k21 = lut[m2 >> 4];
    const float s2e[8] = {sa.x, sa.y, sa.z, sa.w, sb.x, sb.y, sb.z, sb.w};
    float p1[8], p2[8];
    #pragma unroll
    for (int e = 0; e < 8; e++) {
      float sc1 = s1v1 + s2e[e];
      float sc2 = s2e[e] + s1v2;
      sc1 = fmaxf(sc1, ALPHA * sc1);          // leaky-relu (exp2 domain)
      sc2 = fmaxf(sc2, ALPHA * sc2);
      p1[e] = exp2_raw(sc1);
      p2[e] = exp2_raw(sc2);
    }
    u8s af1, af2;
    af1.u[0] = pack2bf(p1[0], p1[1]) & k10.x;
    af1.u[1] = pack2bf(p1[2], p1[3]) & k10.y;
    af1.u[2] = pack2bf(p1[4], p1[5]) & k11.x;
    af1.u[3] = pack2bf(p1[6], p1[7]) & k11.y;
    af2.u[0] = pack2bf(p2[0], p2[1]) & k20.x;
    af2.u[1] = pack2bf(p2[2], p2[3]) & k20.y;
    af2.u[2] = pack2bf(p2[4], p2[5]) & k21.x;
    af2.u[3] = pack2bf(p2[6], p2[7]) & k21.y;
    a10 = __builtin_amdgcn_mfma_f32_16x16x32_bf16(af1.v, b0, a10, 0, 0, 0);
    a20 = __builtin_amdgcn_mfma_f32_16x16x32_bf16(af2.v, b0, a20, 0, 0, 0);
    a11 = __builtin_amdgcn_mfma_f32_16x16x32_bf16(af1.v, b1, a11, 0, 0, 0);
    a21 = __builtin_amdgcn_mfma_f32_16x16x32_bf16(af2.v, b1, a21, 0, 0, 0);
    a12 = __builtin_amdgcn_mfma_f32_16x16x32_bf16(af1.v, b2, a12, 0, 0, 0);
    a22 = __builtin_amdgcn_mfma_f32_16x16x32_bf16(af2.v, b2, a22, 0, 0, 0);
    a13 = __builtin_amdgcn_mfma_f32_16x16x32_bf16(af1.v, b3, a13, 0, 0, 0);
    a23 = __builtin_amdgcn_mfma_f32_16x16x32_bf16(af2.v, b3, a23, 0, 0, 0);
    aS1 = __builtin_amdgcn_mfma_f32_16x16x32_bf16(af1.v, ones.v, aS1, 0, 0, 0);
    aS2 = __builtin_amdgcn_mfma_f32_16x16x32_bf16(af2.v, ones.v, aS2, 0, 0, 0);
  }

  __syncthreads();   // all waves done reading mask_lds/s2_lds before red reuse

  // ---- phase 1: rows i0..i0+15 ----
  #pragma unroll
  for (int r = 0; r < 4; r++) {
    red[w][(kg * 4 + r) * 64 + 0 * 16 + rl] = a10[r];
    red[w][(kg * 4 + r) * 64 + 1 * 16 + rl] = a11[r];
    red[w][(kg * 4 + r) * 64 + 2 * 16 + rl] = a12[r];
    red[w][(kg * 4 + r) * 64 + 3 * 16 + rl] = a13[r];
  }
  if (rl == 0) {
    #pragma unroll
    for (int r = 0; r < 4; r++) ps[w][kg * 4 + r] = aS1[r];
  }
  __syncthreads();
  {
    const int row = t >> 5;
    const int c2 = (t & 31) * 2;
    float den = 0.f, v0 = 0.f, v1 = 0.f;
    #pragma unroll
    for (int s = 0; s < 8; ++s) {
      den += ps[s][row];
      const float* rp = &red[s][row * 64 + c2];
      v0 += rp[0]; v1 += rp[1];
    }
    const float inv = 1.0f / den;
    float2 ov;
    ov.x = elu_f(v0 * inv);
    ov.y = elu_f(v1 * inv);
    *reinterpret_cast<float2*>(
        out + ((long long)b * N_NODES + i0 + row) * FOUT + c2) = ov;
  }
  __syncthreads();

  // ---- phase 2: rows i0+16..i0+31 ----
  #pragma unroll
  for (int r = 0; r < 4; r++) {
    red[w][(kg * 4 + r) * 64 + 0 * 16 + rl] = a20[r];
    red[w][(kg * 4 + r) * 64 + 1 * 16 + rl] = a21[r];
    red[w][(kg * 4 + r) * 64 + 2 * 16 + rl] = a22[r];
    red[w][(kg * 4 + r) * 64 + 3 * 16 + rl] = a23[r];
  }
  if (rl == 0) {
    #pragma unroll
    for (int r = 0; r < 4; r++) ps[w][kg * 4 + r] = aS2[r];
  }
  __syncthreads();
  {
    const int row = t >> 5;
    const int c2 = (t & 31) * 2;
    float den = 0.f, v0 = 0.f, v1 = 0.f;
    #pragma unroll
    for (int s = 0; s < 8; ++s) {
      den += ps[s][row];
      const float* rp = &red[s][row * 64 + c2];
      v0 += rp[0]; v1 += rp[1];
    }
    const float inv = 1.0f / den;
    float2 ov;
    ov.x = elu_f(v0 * inv);
    ov.y = elu_f(v1 * inv);
    *reinterpret_cast<float2*>(
        out + ((long long)b * N_NODES + i0 + 16 + row) * FOUT + c2) = ov;
  }
}

extern "C" void kernel_launch(void* const* d_in, const int* in_sizes, int n_in,
                              void* d_out, int out_size, void* d_ws, size_t ws_size,
                              hipStream_t stream) {
  const float* x   = (const float*)d_in[0];
  const int*   adj = (const int*)d_in[1];
  const float* W   = (const float*)d_in[2];
  const float* a   = (const float*)d_in[3];
  float* out = (float*)d_out;

  short* hp = (short*)d_ws;                                        // 2 MB
  float* s1 = (float*)(hp + (long long)BS * N_NODES * FOUT);       // 64 KB
  float* s2 = s1 + BS * N_NODES;                                   // 64 KB
  unsigned int* mask32 = (unsigned int*)(s2 + BS * N_NODES);       // 512 KB
  short* whi = (short*)(mask32 + N_NODES * 64);                    // 16 KB
  short* wlo = whi + 16 * 64 * 8;                                  // 16 KB

  w_pack<<<16, 64, 0, stream>>>(W, whi, wlo);
  gat_prep<<<1024, 256, 0, stream>>>(x, adj, whi, wlo, a, hp, s1, s2, mask32);
  gat_attn<<<dim3(N_NODES / 32, BS), 512, 0, stream>>>(mask32, hp, s1, s2, out);
}